// Round 5
// baseline (1341.455 us; speedup 1.0000x reference)
//
#include <hip/hip_runtime.h>
#include <math.h>

#define NB 8
#define NA 720
#define NPAIR 360
#define ND 1024
#define NH 512
#define NW 512

// DS = 4/1024 -> 1/DS = 256. S0 = -2 + DS/2 -> -S0/DS = 511.5
#define DXF 0.00390625f
#define IMG_MIN_F (-1.0f)
#define DTH_D (3.14159265358979323846 / 720.0)

#define TI 32            // top-half i rows per block (plus 32 mirrored rows)
#define TJ 32            // j cols per block
#define WIN 64           // staged window elements; tile support <= 44+slack
#define WSTRIDE 224      // words per window block: A at 0..63, B(shifted) at 127..192
#define PSTRIDE (2 * WSTRIDE)

typedef unsigned int uint32;

// ---------------- Kernel 1: 11-tap conv along detector, left pad 10, *DTH -> f16 ----------
__global__ __launch_bounds__(256) void conv_kernel(const float* __restrict__ x,
                                                   const float* __restrict__ w,
                                                   unsigned short* __restrict__ y) {
    int row = blockIdx.x;                 // b*720 + a
    const float* xr = x + (size_t)row * ND;
    unsigned short* yr = y + (size_t)row * ND;

    __shared__ float s[16 + ND];
    __shared__ float wk[16];

    int tid = threadIdx.x;                // 256 threads
    if (tid < 16) s[tid] = 0.0f;
    if (tid < 11) wk[tid] = w[tid] * (float)DTH_D;

    float4 v = ((const float4*)xr)[tid];
    *(float4*)&s[16 + tid * 4] = v;
    __syncthreads();

    int d0 = tid * 4;
    float o0 = 0.f, o1 = 0.f, o2 = 0.f, o3 = 0.f;
#pragma unroll
    for (int k = 0; k < 11; ++k) {
        float wv = wk[k];
        o0 = fmaf(wv, s[6 + d0 + k], o0);
        o1 = fmaf(wv, s[7 + d0 + k], o1);
        o2 = fmaf(wv, s[8 + d0 + k], o2);
        o3 = fmaf(wv, s[9 + d0 + k], o3);
    }
    union { _Float16 h[4]; uint2 u2; } pk;
    pk.h[0] = (_Float16)o0; pk.h[1] = (_Float16)o1;
    pk.h[2] = (_Float16)o2; pk.h[3] = (_Float16)o3;
    *(uint2*)&yr[d0] = pk.u2;             // 8 B aligned (d0*2 = 8*tid)
}

// ---------------- Kernel 2: per-pair tables + per-(tile,pair) window bases ---------------
__global__ __launch_bounds__(256) void table_kernel(float* __restrict__ ct,
                                                    float* __restrict__ st,
                                                    float* __restrict__ cbt) {
    int idx = blockIdx.x * 256 + threadIdx.x;   // 360 pairs * 128 tiles = 46080
    if (idx >= NPAIR * 128) return;
    int p = idx >> 7;
    int t = idx & 127;
    float th = (float)((p + 0.5) * DTH_D);      // THETAS f64->f32 like reference
    double thd = (double)th;
    float ca = (float)(cos(thd) * 256.0);
    float sa = (float)(sin(thd) * 256.0);
    if (t == 0) { ct[p] = ca; st[p] = sa; }

    int it = t >> 4, jt = t & 15;
    int ibase = it * TI, jbase = jt * TJ;
    float pi_lo = IMG_MIN_F + (ibase + 0.5f) * DXF;
    float pi_hi = IMG_MIN_F + (ibase + TI - 0.5f) * DXF;
    float pj_lo = IMG_MIN_F + (jbase + 0.5f) * DXF;
    float pj_hi = IMG_MIN_F + (jbase + TJ - 0.5f) * DXF;
    float sj = fminf(pj_lo * sa, pj_hi * sa);
    float umin1 = 511.5f + fminf(pi_lo * ca, pi_hi * ca) + sj;
    float umin2 = 511.5f + fminf(-pi_lo * ca, -pi_hi * ca) + sj;
    int b1 = ((int)floorf(umin1) - 1) & ~3;     // elem-align 4 -> byte-align 8 in f16
    int b2 = ((int)floorf(umin2) - 1) & ~3;
    b1 = max(0, min(b1, ND - WIN));
    b2 = max(0, min(b2, ND - WIN));
    float* e = cbt + ((size_t)t * NPAIR + p) * 2;
    e[0] = 511.5f - (float)b1;                  // exact integer-valued floats
    e[1] = 511.5f - (float)b2;
}

// ---------------- Kernel 3: backprojection, f16 interleaved windows + fma_mix ------------
// LDS word w[i] = (a[i] f16 lo, a'[i] f16 hi). One u-sample = one ds_read_b64 (8 B):
// (w[iu], w[iu+1]). Dual-copy trick guarantees 8B alignment: copy B[i]=A[i-1] at +127
// words; odd iu reads (B[iu+1], B[iu+2]) at even word index. addr += (iu&1)<<9 bytes.
// Lerp in f32 via v_fma_mix_f32 consuming f16 halves directly (no cvt).

// acc(f32) += lo16(dw) * s(f32)
#define FMIX_LO(acc_, dw_, s_) \
    asm("v_fma_mix_f32 %0, %1, %2, %0 op_sel_hi:[1,0,0]" : "+v"(acc_) : "v"(dw_), "v"(s_))
// acc(f32) += hi16(dw) * s(f32)
#define FMIX_HI(acc_, dw_, s_) \
    asm("v_fma_mix_f32 %0, %1, %2, %0 op_sel:[1,0,0] op_sel_hi:[1,0,0]" : "+v"(acc_) : "v"(dw_), "v"(s_))

__global__ __launch_bounds__(512, 8) void bp_kernel(const unsigned short* __restrict__ sino,
                                                    const float* __restrict__ ct,
                                                    const float* __restrict__ st,
                                                    const float* __restrict__ cbt,
                                                    float* __restrict__ out) {
    int bid = blockIdx.x;
    // XCD-chunked swizzle: XCD x -> all 128 tiles of batch x (1.47 MB f16 sino fits L2)
    int lb = (bid & 7) * 128 + (bid >> 3);
    int b = lb >> 7;
    int tile = lb & 127;
    int it = tile >> 4, jt = tile & 15;
    int ibase = it * TI, jbase = jt * TJ;

    int tid = threadIdx.x;
    int lane = tid & 63;
    int wv = tid >> 6;           // 0..7 -> stages pair c*8+wv
    int jj = lane & 31;
    int hi = lane >> 5;          // 0/1 -> +8 rows
    int sel = lane >> 5;         // staging: 0 -> window1(top), 1 -> window2(bot)
    int e = lane & 31;           // staging dword index (2 f16 elems each)

    int j = jbase + jj;
    float pxj = IMG_MIN_F + (j + 0.5f) * DXF;
    int i0 = ibase + wv + 8 * hi;           // +16*r
    float pxi = IMG_MIN_F + (i0 + 0.5f) * DXF;

    __shared__ __align__(16) uint32 buf[2][8][PSTRIDE];   // 2*8*448*4 = 28672 B

    const unsigned short* srow = sino + (size_t)b * (NA * ND);
    const float* cbrow = cbt + (size_t)tile * NPAIR * 2;

    float accT[2] = {0.f, 0.f};             // pixels (i, j)
    float accM[2] = {0.f, 0.f};             // pixels (511-i, j)
    uint32 dwA, dwB;                        // staged raw f16 pairs (row a / row a')

#define LOADREGS(c_) do { \
    int p_ = (c_) * 8 + wv; \
    float cb_ = cbrow[2 * p_ + sel]; \
    int base_ = (int)(511.5f - cb_); \
    const unsigned short* pa_ = srow + (size_t)p_ * ND + base_ + 2 * e; \
    const unsigned short* pb_ = srow + (size_t)(719 - p_) * ND + base_ + 2 * e; \
    dwA = *(const uint32*)pa_; \
    dwB = *(const uint32*)pb_; \
} while (0)

#define DSWRITE(bsel_) do { \
    uint32 w0_ = (dwA & 0xFFFFu) | (dwB << 16);       /* (a[2e],   a'[2e])   */ \
    uint32 w1_ = (dwA >> 16) | (dwB & 0xFFFF0000u);   /* (a[2e+1], a'[2e+1]) */ \
    uint32* W_ = &buf[bsel_][wv][sel * WSTRIDE + 2 * e]; \
    *(uint2*)W_ = make_uint2(w0_, w1_);               /* copy A, words 2e,2e+1 */ \
    *(uint2*)(W_ + 128) = make_uint2(w0_, w1_);       /* copy B[i]=A[i-1] at +127 */ \
} while (0)

    LOADREGS(0);
    DSWRITE(0);
    __syncthreads();

    for (int c = 0; c < 45; ++c) {
        int cur = c & 1;
        if (c + 1 < 45) LOADREGS(c + 1);    // issue early; latency hides under compute
        const uint32* pb0 = &buf[cur][0][0];
#pragma unroll
        for (int k = 0; k < 8; ++k) {
            int p = c * 8 + k;
            float ca = ct[p];                  // uniform -> s_load
            float sa = st[p];
            float cb1 = cbrow[2 * p];
            float cb2 = cbrow[2 * p + 1];
            float du = ca * (16.0f * DXF);
            float u1 = fmaf(pxj, sa, fmaf(pxi, ca, cb1));    // local in window1
            float u2 = fmaf(pxj, sa, fmaf(pxi, -ca, cb2));   // local in window2
            const uint32* w1b = pb0 + k * PSTRIDE;
            const uint32* w2b = w1b + WSTRIDE;
#pragma unroll
            for (int r = 0; r < 2; ++r) {
                // ---- u1: word lo = row a -> T, hi = row a' -> M
                int iu1 = (int)u1;                    // u1 in [1,51): trunc == floor
                float f1 = __builtin_amdgcn_fractf(u1);
                float g1 = 1.0f - f1;
                uint2 q1 = *(const uint2*)(w1b + iu1 + ((iu1 & 1) << 7));  // ds_read_b64
                FMIX_LO(accT[r], q1.x, g1);
                FMIX_LO(accT[r], q1.y, f1);
                FMIX_HI(accM[r], q1.x, g1);
                FMIX_HI(accM[r], q1.y, f1);

                // ---- u2: word lo = row a -> M, hi = row a' -> T
                int iu2 = (int)u2;
                float f2 = __builtin_amdgcn_fractf(u2);
                float g2 = 1.0f - f2;
                uint2 q2 = *(const uint2*)(w2b + iu2 + ((iu2 & 1) << 7));  // ds_read_b64
                FMIX_LO(accM[r], q2.x, g2);
                FMIX_LO(accM[r], q2.y, f2);
                FMIX_HI(accT[r], q2.x, g2);
                FMIX_HI(accT[r], q2.y, f2);

                u1 += du;
                u2 -= du;
            }
        }
        if (c + 1 < 45) DSWRITE(cur ^ 1);   // pack + write; vmcnt wait lands here
        __syncthreads();
    }

    float* orow = out + (size_t)b * (NH * NW);
#pragma unroll
    for (int r = 0; r < 2; ++r) {
        int i = i0 + 16 * r;
        orow[i * NW + j] = accT[r];
        orow[(511 - i) * NW + j] = accM[r];
    }
#undef LOADREGS
#undef DSWRITE
}

extern "C" void kernel_launch(void* const* d_in, const int* in_sizes, int n_in,
                              void* d_out, int out_size, void* d_ws, size_t ws_size,
                              hipStream_t stream) {
    const float* x = (const float*)d_in[0];      // [8,1,720,1024] f32
    const float* w = (const float*)d_in[1];      // [1,1,1,11] f32
    float* out = (float*)d_out;                  // [8,1,512,512] f32

    unsigned short* sino = (unsigned short*)d_ws;        // 8*720*1024 f16 = 11.8 MB
    float* ct = (float*)(sino + (size_t)NB * NA * ND);   // 360 floats
    float* st = ct + NPAIR;                              // 360 floats
    float* cbt = st + NPAIR;                             // 128*360*2 floats = 368 KB

    conv_kernel<<<dim3(NB * NA), dim3(256), 0, stream>>>(x, w, sino);
    table_kernel<<<dim3(180), dim3(256), 0, stream>>>(ct, st, cbt);
    bp_kernel<<<dim3(1024), dim3(512), 0, stream>>>(sino, ct, st, cbt, out);
}

// Round 6
// 295.056 us; speedup vs baseline: 4.5464x; 4.5464x over previous
//
#include <hip/hip_runtime.h>
#include <math.h>

#define NB 8
#define NA 720
#define NPAIR 360
#define ND 1024
#define NH 512
#define NW 512

// DS = 4/1024 -> 1/DS = 256. S0 = -2 + DS/2 -> -S0/DS = 511.5
#define DXF 0.00390625f
#define IMG_MIN_F (-1.0f)
#define DTH_D (3.14159265358979323846 / 720.0)

#define TI 32            // top-half i rows per block (plus 32 mirrored rows)
#define TJ 32            // j cols per block
#define WIN 64           // staged window elements; tile support <= 44+slack
#define WPAD 66          // words per window (64 + 2 pad, even -> keeps 8B alignment)

typedef unsigned int uint32;

// ---------------- Kernel 1: 11-tap conv along detector, left pad 10, *DTH -> f16 ----------
__global__ __launch_bounds__(256) void conv_kernel(const float* __restrict__ x,
                                                   const float* __restrict__ w,
                                                   unsigned short* __restrict__ y) {
    int row = blockIdx.x;                 // b*720 + a
    const float* xr = x + (size_t)row * ND;
    unsigned short* yr = y + (size_t)row * ND;

    __shared__ float s[16 + ND];
    __shared__ float wk[16];

    int tid = threadIdx.x;                // 256 threads
    if (tid < 16) s[tid] = 0.0f;
    if (tid < 11) wk[tid] = w[tid] * (float)DTH_D;

    float4 v = ((const float4*)xr)[tid];
    *(float4*)&s[16 + tid * 4] = v;
    __syncthreads();

    int d0 = tid * 4;
    float o0 = 0.f, o1 = 0.f, o2 = 0.f, o3 = 0.f;
#pragma unroll
    for (int k = 0; k < 11; ++k) {
        float wv = wk[k];
        o0 = fmaf(wv, s[6 + d0 + k], o0);
        o1 = fmaf(wv, s[7 + d0 + k], o1);
        o2 = fmaf(wv, s[8 + d0 + k], o2);
        o3 = fmaf(wv, s[9 + d0 + k], o3);
    }
    union { _Float16 h[4]; uint2 u2; } pk;
    pk.h[0] = (_Float16)o0; pk.h[1] = (_Float16)o1;
    pk.h[2] = (_Float16)o2; pk.h[3] = (_Float16)o3;
    *(uint2*)&yr[d0] = pk.u2;             // 8 B aligned (d0*2 = 8*tid)
}

// ---------------- Kernel 2: per-pair tables + per-(tile,pair) window bases ---------------
__global__ __launch_bounds__(256) void table_kernel(float* __restrict__ ct,
                                                    float* __restrict__ st,
                                                    float* __restrict__ cbt) {
    int idx = blockIdx.x * 256 + threadIdx.x;   // 360 pairs * 128 tiles = 46080
    if (idx >= NPAIR * 128) return;
    int p = idx >> 7;
    int t = idx & 127;
    float th = (float)((p + 0.5) * DTH_D);      // THETAS f64->f32 like reference
    double thd = (double)th;
    float ca = (float)(cos(thd) * 256.0);
    float sa = (float)(sin(thd) * 256.0);
    if (t == 0) { ct[p] = ca; st[p] = sa; }

    int it = t >> 4, jt = t & 15;
    int ibase = it * TI, jbase = jt * TJ;
    float pi_lo = IMG_MIN_F + (ibase + 0.5f) * DXF;
    float pi_hi = IMG_MIN_F + (ibase + TI - 0.5f) * DXF;
    float pj_lo = IMG_MIN_F + (jbase + 0.5f) * DXF;
    float pj_hi = IMG_MIN_F + (jbase + TJ - 0.5f) * DXF;
    float sj = fminf(pj_lo * sa, pj_hi * sa);
    float umin1 = 511.5f + fminf(pi_lo * ca, pi_hi * ca) + sj;
    float umin2 = 511.5f + fminf(-pi_lo * ca, -pi_hi * ca) + sj;
    int b1 = ((int)floorf(umin1) - 1) & ~3;     // elem-align 4 -> byte-align 8 in f16
    int b2 = ((int)floorf(umin2) - 1) & ~3;
    b1 = max(0, min(b1, ND - WIN));
    b2 = max(0, min(b2, ND - WIN));
    float* e = cbt + ((size_t)t * NPAIR + p) * 2;
    e[0] = 511.5f - (float)b1;                  // exact integer-valued floats
    e[1] = 511.5f - (float)b2;
}

// ---------------- Kernel 3: backprojection, f16 interleaved windows + ds_read2_b32 -------
// LDS word W[i] = (a[i] f16 lo, a'[i] f16 hi). One u-sample reads W[iu], W[iu+1]:
// two adjacent dword loads off one base -> compiler merges to ONE ds_read2_b32
// (4B-aligned, any iu parity -- no alignment games, no dual copy).
// Lerp in f32 via v_fma_mix_f32 consuming f16 halves directly (no cvt).

// acc(f32) += lo16(dw) * s(f32)
#define FMIX_LO(acc_, dw_, s_) \
    asm("v_fma_mix_f32 %0, %1, %2, %0 op_sel_hi:[1,0,0]" : "+v"(acc_) : "v"(dw_), "v"(s_))
// acc(f32) += hi16(dw) * s(f32)
#define FMIX_HI(acc_, dw_, s_) \
    asm("v_fma_mix_f32 %0, %1, %2, %0 op_sel:[1,0,0] op_sel_hi:[1,0,0]" : "+v"(acc_) : "v"(dw_), "v"(s_))

__global__ __launch_bounds__(512, 8) void bp_kernel(const unsigned short* __restrict__ sino,
                                                    const float* __restrict__ ct,
                                                    const float* __restrict__ st,
                                                    const float* __restrict__ cbt,
                                                    float* __restrict__ out) {
    int bid = blockIdx.x;
    // XCD-chunked swizzle: XCD x -> all 128 tiles of batch x (1.47 MB f16 sino fits L2)
    int lb = (bid & 7) * 128 + (bid >> 3);
    int b = lb >> 7;
    int tile = lb & 127;
    int it = tile >> 4, jt = tile & 15;
    int ibase = it * TI, jbase = jt * TJ;

    int tid = threadIdx.x;
    int lane = tid & 63;
    int wv = tid >> 6;           // 0..7 -> stages pair c*8+wv
    int jj = lane & 31;
    int hi = lane >> 5;          // 0/1 -> +8 rows
    int sel = lane >> 5;         // staging: 0 -> window1(top), 1 -> window2(bot)
    int e = lane & 31;           // staging dword index (2 f16 elems each)

    int j = jbase + jj;
    float pxj = IMG_MIN_F + (j + 0.5f) * DXF;
    int i0 = ibase + wv + 8 * hi;           // +16*r
    float pxi = IMG_MIN_F + (i0 + 0.5f) * DXF;

    __shared__ __align__(16) uint32 buf[2][8][2][WPAD];   // 2*8*2*66*4 = 8448 B

    const unsigned short* srow = sino + (size_t)b * (NA * ND);
    const float* cbrow = cbt + (size_t)tile * NPAIR * 2;

    float accT[2] = {0.f, 0.f};             // pixels (i, j)
    float accM[2] = {0.f, 0.f};             // pixels (511-i, j)
    uint32 dwA, dwB;                        // staged raw f16 pairs (row a / row a')

#define LOADREGS(c_) do { \
    int p_ = (c_) * 8 + wv; \
    float cb_ = cbrow[2 * p_ + sel]; \
    int base_ = (int)(511.5f - cb_); \
    const unsigned short* pa_ = srow + (size_t)p_ * ND + base_ + 2 * e; \
    const unsigned short* pb_ = srow + (size_t)(719 - p_) * ND + base_ + 2 * e; \
    dwA = *(const uint32*)pa_; \
    dwB = *(const uint32*)pb_; \
} while (0)

#define DSWRITE(bsel_) do { \
    uint32 w0_ = (dwA & 0xFFFFu) | (dwB << 16);       /* (a[2e],   a'[2e])   */ \
    uint32 w1_ = (dwA >> 16) | (dwB & 0xFFFF0000u);   /* (a[2e+1], a'[2e+1]) */ \
    uint32* W_ = &buf[bsel_][wv][sel][2 * e];         /* even word, 8B-aligned */ \
    *(uint2*)W_ = make_uint2(w0_, w1_); \
} while (0)

    LOADREGS(0);
    DSWRITE(0);
    __syncthreads();

    for (int c = 0; c < 45; ++c) {
        int cur = c & 1;
        if (c + 1 < 45) LOADREGS(c + 1);    // issue early; latency hides under compute
#pragma unroll
        for (int k = 0; k < 8; ++k) {
            int p = c * 8 + k;
            float ca = ct[p];                  // uniform -> s_load
            float sa = st[p];
            float cb1 = cbrow[2 * p];
            float cb2 = cbrow[2 * p + 1];
            float du = ca * (16.0f * DXF);
            float u1 = fmaf(pxj, sa, fmaf(pxi, ca, cb1));    // local in window1
            float u2 = fmaf(pxj, sa, fmaf(pxi, -ca, cb2));   // local in window2
            const uint32* w1b = &buf[cur][k][0][0];
            const uint32* w2b = &buf[cur][k][1][0];
#pragma unroll
            for (int r = 0; r < 2; ++r) {
                // ---- u1: word lo16 = row a -> T, hi16 = row a' -> M
                int iu1 = (int)u1;                    // u1 in [1,51): trunc == floor
                float f1 = __builtin_amdgcn_fractf(u1);
                float g1 = 1.0f - f1;
                uint32 qa = w1b[iu1];                 // merge -> ds_read2_b32
                uint32 qb = w1b[iu1 + 1];
                FMIX_LO(accT[r], qa, g1);
                FMIX_LO(accT[r], qb, f1);
                FMIX_HI(accM[r], qa, g1);
                FMIX_HI(accM[r], qb, f1);

                // ---- u2: word lo16 = row a -> M, hi16 = row a' -> T
                int iu2 = (int)u2;
                float f2 = __builtin_amdgcn_fractf(u2);
                float g2 = 1.0f - f2;
                uint32 xa = w2b[iu2];                 // merge -> ds_read2_b32
                uint32 xb = w2b[iu2 + 1];
                FMIX_LO(accM[r], xa, g2);
                FMIX_LO(accM[r], xb, f2);
                FMIX_HI(accT[r], xa, g2);
                FMIX_HI(accT[r], xb, f2);

                u1 += du;
                u2 -= du;
            }
        }
        if (c + 1 < 45) DSWRITE(cur ^ 1);   // pack + write; vmcnt wait lands here
        __syncthreads();
    }

    float* orow = out + (size_t)b * (NH * NW);
#pragma unroll
    for (int r = 0; r < 2; ++r) {
        int i = i0 + 16 * r;
        orow[i * NW + j] = accT[r];
        orow[(511 - i) * NW + j] = accM[r];
    }
#undef LOADREGS
#undef DSWRITE
}

extern "C" void kernel_launch(void* const* d_in, const int* in_sizes, int n_in,
                              void* d_out, int out_size, void* d_ws, size_t ws_size,
                              hipStream_t stream) {
    const float* x = (const float*)d_in[0];      // [8,1,720,1024] f32
    const float* w = (const float*)d_in[1];      // [1,1,1,11] f32
    float* out = (float*)d_out;                  // [8,1,512,512] f32

    unsigned short* sino = (unsigned short*)d_ws;        // 8*720*1024 f16 = 11.8 MB
    float* ct = (float*)(sino + (size_t)NB * NA * ND);   // 360 floats
    float* st = ct + NPAIR;                              // 360 floats
    float* cbt = st + NPAIR;                             // 128*360*2 floats = 368 KB

    conv_kernel<<<dim3(NB * NA), dim3(256), 0, stream>>>(x, w, sino);
    table_kernel<<<dim3(180), dim3(256), 0, stream>>>(ct, st, cbt);
    bp_kernel<<<dim3(1024), dim3(512), 0, stream>>>(sino, ct, st, cbt, out);
}

// Round 7
// 277.638 us; speedup vs baseline: 4.8317x; 1.0627x over previous
//
#include <hip/hip_runtime.h>
#include <math.h>

#define NB 8
#define NA 720
#define NPAIR 360
#define ND 1024
#define NH 512
#define NW 512

// DS = 4/1024 -> 1/DS = 256. S0 = -2 + DS/2 -> -S0/DS = 511.5
#define DXF 0.00390625f
#define IMG_MIN_F (-1.0f)
#define DTH_D (3.14159265358979323846 / 720.0)

#define TI 32            // top-half i rows per block (plus 32 mirrored rows)
#define TJ 32            // j cols per block
#define WIN 64           // staged window elements; u stays in [1, ~50]

typedef unsigned int uint32;

// ---------------- Kernel 1: 11-tap conv along detector, left pad 10, *DTH -> f16 ----------
__global__ __launch_bounds__(256) void conv_kernel(const float* __restrict__ x,
                                                   const float* __restrict__ w,
                                                   unsigned short* __restrict__ y) {
    int row = blockIdx.x;                 // b*720 + a
    const float* xr = x + (size_t)row * ND;
    unsigned short* yr = y + (size_t)row * ND;

    __shared__ float s[16 + ND];
    __shared__ float wk[16];

    int tid = threadIdx.x;                // 256 threads
    if (tid < 16) s[tid] = 0.0f;
    if (tid < 11) wk[tid] = w[tid] * (float)DTH_D;

    float4 v = ((const float4*)xr)[tid];
    *(float4*)&s[16 + tid * 4] = v;
    __syncthreads();

    int d0 = tid * 4;
    float o0 = 0.f, o1 = 0.f, o2 = 0.f, o3 = 0.f;
#pragma unroll
    for (int k = 0; k < 11; ++k) {
        float wv = wk[k];
        o0 = fmaf(wv, s[6 + d0 + k], o0);
        o1 = fmaf(wv, s[7 + d0 + k], o1);
        o2 = fmaf(wv, s[8 + d0 + k], o2);
        o3 = fmaf(wv, s[9 + d0 + k], o3);
    }
    union { _Float16 h[4]; uint2 u2; } pk;
    pk.h[0] = (_Float16)o0; pk.h[1] = (_Float16)o1;
    pk.h[2] = (_Float16)o2; pk.h[3] = (_Float16)o3;
    *(uint2*)&yr[d0] = pk.u2;             // 8 B aligned (d0*2 = 8*tid)
}

// ---------------- Kernel 2: per-pair tables + per-(tile,pair) window bases ---------------
__global__ __launch_bounds__(256) void table_kernel(float* __restrict__ ct,
                                                    float* __restrict__ st,
                                                    float* __restrict__ cbt) {
    int idx = blockIdx.x * 256 + threadIdx.x;   // 360 pairs * 128 tiles = 46080
    if (idx >= NPAIR * 128) return;
    int p = idx >> 7;
    int t = idx & 127;
    float th = (float)((p + 0.5) * DTH_D);      // THETAS f64->f32 like reference
    double thd = (double)th;
    float ca = (float)(cos(thd) * 256.0);
    float sa = (float)(sin(thd) * 256.0);
    if (t == 0) { ct[p] = ca; st[p] = sa; }

    int it = t >> 4, jt = t & 15;
    int ibase = it * TI, jbase = jt * TJ;
    float pi_lo = IMG_MIN_F + (ibase + 0.5f) * DXF;
    float pi_hi = IMG_MIN_F + (ibase + TI - 0.5f) * DXF;
    float pj_lo = IMG_MIN_F + (jbase + 0.5f) * DXF;
    float pj_hi = IMG_MIN_F + (jbase + TJ - 0.5f) * DXF;
    float sj = fminf(pj_lo * sa, pj_hi * sa);
    float umin1 = 511.5f + fminf(pi_lo * ca, pi_hi * ca) + sj;
    float umin2 = 511.5f + fminf(-pi_lo * ca, -pi_hi * ca) + sj;
    int b1 = ((int)floorf(umin1) - 1) & ~3;     // elem-align 4 -> 4B-aligned f16 loads
    int b2 = ((int)floorf(umin2) - 1) & ~3;
    b1 = max(0, min(b1, ND - WIN));
    b2 = max(0, min(b2, ND - WIN));
    float* e = cbt + ((size_t)t * NPAIR + p) * 2;
    e[0] = 511.5f - (float)b1;                  // exact integer-valued floats
    e[1] = 511.5f - (float)b2;
}

// ---------------- Kernel 3: backprojection, duplicate-neighbor f16 windows ---------------
// LDS element V[i] (uint2, 8B): .x = (a[i] f16 lo | a[i+1] f16 hi), .y = same for a'.
// One u-sample = ONE naturally-aligned ds_read_b64 of V[iu]; both taps of both rows
// are consumed via v_fma_mix_f32 (f16 halves in f32 precision, no cvt).
// Neighbor duplication is built at write time: V[2e+1].x = (dwA>>16)|(shfl(dwA,lane+1)<<16).

// acc(f32) += lo16(dw) * s(f32)
#define FMIX_LO(acc_, dw_, s_) \
    asm("v_fma_mix_f32 %0, %1, %2, %0 op_sel_hi:[1,0,0]" : "+v"(acc_) : "v"(dw_), "v"(s_))
// acc(f32) += hi16(dw) * s(f32)
#define FMIX_HI(acc_, dw_, s_) \
    asm("v_fma_mix_f32 %0, %1, %2, %0 op_sel:[1,0,0] op_sel_hi:[1,0,0]" : "+v"(acc_) : "v"(dw_), "v"(s_))

__global__ __launch_bounds__(512, 8) void bp_kernel(const unsigned short* __restrict__ sino,
                                                    const float* __restrict__ ct,
                                                    const float* __restrict__ st,
                                                    const float* __restrict__ cbt,
                                                    float* __restrict__ out) {
    int bid = blockIdx.x;
    // XCD-chunked swizzle: XCD x -> all 128 tiles of batch x (1.47 MB f16 sino fits L2)
    int lb = (bid & 7) * 128 + (bid >> 3);
    int b = lb >> 7;
    int tile = lb & 127;
    int it = tile >> 4, jt = tile & 15;
    int ibase = it * TI, jbase = jt * TJ;

    int tid = threadIdx.x;
    int lane = tid & 63;
    int wv = tid >> 6;           // 0..7 -> stages pair c*8+wv
    int jj = lane & 31;
    int hi = lane >> 5;          // 0/1 -> +8 rows
    int sel = lane >> 5;         // staging: 0 -> window1(top), 1 -> window2(bot)
    int e = lane & 31;           // staging dword index (2 f16 elems each)

    int j = jbase + jj;
    float pxj = IMG_MIN_F + (j + 0.5f) * DXF;
    int i0 = ibase + wv + 8 * hi;           // +16*r
    float pxi = IMG_MIN_F + (i0 + 0.5f) * DXF;

    __shared__ __align__(16) uint2 buf[2][8][2][WIN];   // 2*8*2*64*8 = 16384 B

    const unsigned short* srow = sino + (size_t)b * (NA * ND);
    const float* cbrow = cbt + (size_t)tile * NPAIR * 2;

    float accT[2] = {0.f, 0.f};             // pixels (i, j)
    float accM[2] = {0.f, 0.f};             // pixels (511-i, j)
    uint32 dwA, dwB;                        // staged raw f16 pairs (row a / row a')

#define LOADREGS(c_) do { \
    int p_ = (c_) * 8 + wv; \
    float cb_ = cbrow[2 * p_ + sel]; \
    int base_ = (int)(511.5f - cb_); \
    const unsigned short* pa_ = srow + (size_t)p_ * ND + base_ + 2 * e; \
    const unsigned short* pb_ = srow + (size_t)(719 - p_) * ND + base_ + 2 * e; \
    dwA = *(const uint32*)pa_; \
    dwB = *(const uint32*)pb_; \
} while (0)

    // V[2e]   = (dwA, dwB)                       -- elems (2e, 2e+1)
    // V[2e+1] = (align(dwA2,dwA), align(dwB2,dwB)) -- elems (2e+1, 2e+2)
    // seam (e=31) writes garbage into V[63], which is never read (iu <= ~50).
#define DSWRITE(bsel_) do { \
    uint32 a2_ = (uint32)__shfl((int)dwA, lane + 1, 64); \
    uint32 b2_ = (uint32)__shfl((int)dwB, lane + 1, 64); \
    uint2* V_ = &buf[bsel_][wv][sel][2 * e]; \
    V_[0] = make_uint2(dwA, dwB); \
    V_[1] = make_uint2((dwA >> 16) | (a2_ << 16), (dwB >> 16) | (b2_ << 16)); \
} while (0)

    LOADREGS(0);
    DSWRITE(0);
    __syncthreads();

    for (int c = 0; c < 45; ++c) {
        int cur = c & 1;
        if (c + 1 < 45) LOADREGS(c + 1);    // issue early; latency hides under compute
#pragma unroll
        for (int k = 0; k < 8; ++k) {
            int p = c * 8 + k;
            float ca = ct[p];                  // uniform -> s_load
            float sa = st[p];
            float cb1 = cbrow[2 * p];
            float cb2 = cbrow[2 * p + 1];
            float du = ca * (16.0f * DXF);
            float u1 = fmaf(pxj, sa, fmaf(pxi, ca, cb1));    // local in window1
            float u2 = fmaf(pxj, sa, fmaf(pxi, -ca, cb2));   // local in window2
            const uint2* w1b = &buf[cur][k][0][0];
            const uint2* w2b = &buf[cur][k][1][0];
#pragma unroll
            for (int r = 0; r < 2; ++r) {
                // ---- u1: V.x = row a (taps iu,iu+1) -> T ; V.y = row a' -> M
                int iu1 = (int)u1;                    // u1 in [1,51): trunc == floor
                float f1 = __builtin_amdgcn_fractf(u1);
                float g1 = 1.0f - f1;
                uint2 q1 = w1b[iu1];                  // one ds_read_b64
                FMIX_LO(accT[r], q1.x, g1);
                FMIX_HI(accT[r], q1.x, f1);
                FMIX_LO(accM[r], q1.y, g1);
                FMIX_HI(accM[r], q1.y, f1);

                // ---- u2: V.x = row a -> M ; V.y = row a' -> T
                int iu2 = (int)u2;
                float f2 = __builtin_amdgcn_fractf(u2);
                float g2 = 1.0f - f2;
                uint2 q2 = w2b[iu2];                  // one ds_read_b64
                FMIX_LO(accM[r], q2.x, g2);
                FMIX_HI(accM[r], q2.x, f2);
                FMIX_LO(accT[r], q2.y, g2);
                FMIX_HI(accT[r], q2.y, f2);

                u1 += du;
                u2 -= du;
            }
        }
        if (c + 1 < 45) DSWRITE(cur ^ 1);   // shfl + pack + 16B write; vmcnt wait here
        __syncthreads();
    }

    float* orow = out + (size_t)b * (NH * NW);
#pragma unroll
    for (int r = 0; r < 2; ++r) {
        int i = i0 + 16 * r;
        orow[i * NW + j] = accT[r];
        orow[(511 - i) * NW + j] = accM[r];
    }
#undef LOADREGS
#undef DSWRITE
}

extern "C" void kernel_launch(void* const* d_in, const int* in_sizes, int n_in,
                              void* d_out, int out_size, void* d_ws, size_t ws_size,
                              hipStream_t stream) {
    const float* x = (const float*)d_in[0];      // [8,1,720,1024] f32
    const float* w = (const float*)d_in[1];      // [1,1,1,11] f32
    float* out = (float*)d_out;                  // [8,1,512,512] f32

    unsigned short* sino = (unsigned short*)d_ws;        // 8*720*1024 f16 = 11.8 MB
    float* ct = (float*)(sino + (size_t)NB * NA * ND);   // 360 floats
    float* st = ct + NPAIR;                              // 360 floats
    float* cbt = st + NPAIR;                             // 128*360*2 floats = 368 KB

    conv_kernel<<<dim3(NB * NA), dim3(256), 0, stream>>>(x, w, sino);
    table_kernel<<<dim3(180), dim3(256), 0, stream>>>(ct, st, cbt);
    bp_kernel<<<dim3(1024), dim3(512), 0, stream>>>(sino, ct, st, cbt, out);
}

// Round 9
// 274.640 us; speedup vs baseline: 4.8844x; 1.0109x over previous
//
#include <hip/hip_runtime.h>
#include <math.h>

#define NB 8
#define NA 720
#define NPAIR 360
#define ND 1024
#define NH 512
#define NW 512

// DS = 4/1024 -> 1/DS = 256. S0 = -2 + DS/2 -> -S0/DS = 511.5
#define DXF 0.00390625f
#define IMG_MIN_F (-1.0f)
#define DTH_D (3.14159265358979323846 / 720.0)

#define TI 32            // top-half i rows per block (plus 32 mirrored rows)
#define TJ 32            // j cols per block
#define WIN 128          // staged window elements (1 KB = one global_load_lds per wave)

typedef unsigned int uint32;
typedef __fp16 half2v __attribute__((ext_vector_type(2)));   // matches cvt_pkrtz return

// ---------------- Kernel 1: 11-tap conv on angle PAIR (p, 719-p) -> interleaved f16 G2 ----
// G2[b][p][d] (uint2): .x = pack(y_p[d], y_p[d+1]) f16x2 ; .y = same for row 719-p.
__global__ __launch_bounds__(256) void conv_kernel(const float* __restrict__ x,
                                                   const float* __restrict__ w,
                                                   uint2* __restrict__ G2) {
    int id = blockIdx.x;                  // b*360 + p
    int b = id / NPAIR;
    int p = id - b * NPAIR;
    const float* xr0 = x + ((size_t)b * NA + p) * ND;
    const float* xr1 = x + ((size_t)b * NA + (719 - p)) * ND;

    __shared__ float s[2][16 + ND];
    __shared__ unsigned short hh[2][ND + 8];
    __shared__ float wk[16];

    int tid = threadIdx.x;                // 256 threads
    if (tid < 16) { s[0][tid] = 0.0f; s[1][tid] = 0.0f; }
    if (tid < 11) wk[tid] = w[tid] * (float)DTH_D;
    if (tid < 8)  { hh[0][ND + tid] = 0; hh[1][ND + tid] = 0; }

    *(float4*)&s[0][16 + tid * 4] = ((const float4*)xr0)[tid];
    *(float4*)&s[1][16 + tid * 4] = ((const float4*)xr1)[tid];
    __syncthreads();

    int d0 = tid * 4;
#pragma unroll
    for (int r = 0; r < 2; ++r) {
        float o0 = 0.f, o1 = 0.f, o2 = 0.f, o3 = 0.f;
#pragma unroll
        for (int k = 0; k < 11; ++k) {
            float wv = wk[k];
            o0 = fmaf(wv, s[r][6 + d0 + k], o0);
            o1 = fmaf(wv, s[r][7 + d0 + k], o1);
            o2 = fmaf(wv, s[r][8 + d0 + k], o2);
            o3 = fmaf(wv, s[r][9 + d0 + k], o3);
        }
        union { _Float16 h[4]; uint2 u2; } pk;
        pk.h[0] = (_Float16)o0; pk.h[1] = (_Float16)o1;
        pk.h[2] = (_Float16)o2; pk.h[3] = (_Float16)o3;
        *(uint2*)&hh[r][d0] = pk.u2;      // 8B-aligned (2*d0 = 8*tid)
    }
    __syncthreads();

    uint32 a0 = *(const uint32*)&hh[0][d0];
    uint32 a1 = *(const uint32*)&hh[0][d0 + 2];
    uint32 a2 = *(const uint32*)&hh[0][d0 + 4];
    uint32 c0 = *(const uint32*)&hh[1][d0];
    uint32 c1 = *(const uint32*)&hh[1][d0 + 2];
    uint32 c2 = *(const uint32*)&hh[1][d0 + 4];

    uint2* gout = G2 + ((size_t)b * NPAIR + p) * ND + d0;
    gout[0] = make_uint2(a0, c0);
    gout[1] = make_uint2((a0 >> 16) | (a1 << 16), (c0 >> 16) | (c1 << 16));
    gout[2] = make_uint2(a1, c1);
    gout[3] = make_uint2((a1 >> 16) | (a2 << 16), (c1 >> 16) | (c2 << 16));
}

// ---------------- Kernel 2: fused per-(tile,pair) table: (ca, sa, 511.5-b1, 511.5-b2) ----
__global__ __launch_bounds__(256) void table_kernel(float4* __restrict__ tpr) {
    int idx = blockIdx.x * 256 + threadIdx.x;   // 360 pairs * 128 tiles = 46080
    if (idx >= NPAIR * 128) return;
    int p = idx >> 7;
    int t = idx & 127;
    float th = (float)((p + 0.5) * DTH_D);      // THETAS f64->f32 like reference
    double thd = (double)th;
    float ca = (float)(cos(thd) * 256.0);
    float sa = (float)(sin(thd) * 256.0);

    int it = t >> 4, jt = t & 15;
    int ibase = it * TI, jbase = jt * TJ;
    float pi_lo = IMG_MIN_F + (ibase + 0.5f) * DXF;
    float pi_hi = IMG_MIN_F + (ibase + TI - 0.5f) * DXF;
    float pj_lo = IMG_MIN_F + (jbase + 0.5f) * DXF;
    float pj_hi = IMG_MIN_F + (jbase + TJ - 0.5f) * DXF;
    float sj = fminf(pj_lo * sa, pj_hi * sa);
    float umin1 = 511.5f + fminf(pi_lo * ca, pi_hi * ca) + sj;
    float umin2 = 511.5f + fminf(-pi_lo * ca, -pi_hi * ca) + sj;
    int b1 = ((int)floorf(umin1) - 1) & ~3;     // 4-elem align -> 32B align in G2
    int b2 = ((int)floorf(umin2) - 1) & ~3;
    b1 = max(0, min(b1, ND - WIN));
    b2 = max(0, min(b2, ND - WIN));
    tpr[(size_t)t * NPAIR + p] =
        make_float4(ca, sa, 511.5f - (float)b1, 511.5f - (float)b2);
}

// ---------------- Kernel 3: backprojection, async-DMA windows + dot2 lerp ---------------
// Per chunk: 8 pairs; wave wv DMA-stages pair (c*8+wv)'s two 1 KB windows straight from
// G2 (already interleaved+duplicated) via global_load_lds_dwordx4 -- zero staging VALU.
// One u-sample = one ds_read_b64 (V[iu]) + v_dot2_f32_f16 per row with (g,f) packed once.

__device__ __forceinline__ void async_ld16(const float* g, float* l) {
    __builtin_amdgcn_global_load_lds((const __attribute__((address_space(1))) void*)g,
                                     (__attribute__((address_space(3))) void*)l,
                                     16, 0, 0);
}

#define WAIT_VM0_BARRIER() do { \
    asm volatile("" ::: "memory"); \
    __builtin_amdgcn_s_waitcnt(0x0F70); /* vmcnt(0) only */ \
    __builtin_amdgcn_s_barrier(); \
    asm volatile("" ::: "memory"); \
} while (0)

// acc(f32) += taps.lo16 * gf.lo + taps.hi16 * gf.hi   (one VOP3P dot2)
#define DOT2(acc_, taps_, gf_) \
    asm("v_dot2_f32_f16 %0, %1, %2, %0" : "+v"(acc_) : "v"(taps_), "v"(gf_))

__global__ __launch_bounds__(512, 8) void bp_kernel(const uint2* __restrict__ G2,
                                                    const float4* __restrict__ tpr,
                                                    float* __restrict__ out) {
    int bid = blockIdx.x;
    // XCD-chunked swizzle: XCD x -> all 128 tiles of batch x (2.95 MB G2 slice fits L2)
    int lb = (bid & 7) * 128 + (bid >> 3);
    int b = lb >> 7;
    int tile = lb & 127;
    int it = tile >> 4, jt = tile & 15;
    int ibase = it * TI, jbase = jt * TJ;

    int tid = threadIdx.x;
    int lane = tid & 63;
    int wv = tid >> 6;           // 0..7 -> stages pair c*8+wv
    int jj = lane & 31;
    int hi = lane >> 5;          // 0/1 -> +8 rows

    int j = jbase + jj;
    float pxj = IMG_MIN_F + (j + 0.5f) * DXF;
    int i0 = ibase + wv + 8 * hi;           // +16*r
    float pxi = IMG_MIN_F + (i0 + 0.5f) * DXF;

    __shared__ __align__(16) uint2 buf[2][8][2][WIN];   // 2*8*2*128*8 = 32768 B

    const uint2* gp = G2 + (size_t)b * (NPAIR * ND);
    const float4* tp = tpr + (size_t)tile * NPAIR;

    float accT[2] = {0.f, 0.f};             // pixels (i, j)
    float accM[2] = {0.f, 0.f};             // pixels (511-i, j)

#define STAGE(c_, bs_) do { \
    int p_ = (c_) * 8 + wv; \
    float4 t4_ = tp[p_]; \
    int b1_ = (int)(511.5f - t4_.z); \
    int b2_ = (int)(511.5f - t4_.w); \
    const float* g1_ = (const float*)(gp + (size_t)p_ * ND + b1_) + lane * 4; \
    const float* g2_ = (const float*)(gp + (size_t)p_ * ND + b2_) + lane * 4; \
    async_ld16(g1_, (float*)&buf[bs_][wv][0][0]); \
    async_ld16(g2_, (float*)&buf[bs_][wv][1][0]); \
} while (0)

    STAGE(0, 0);
    WAIT_VM0_BARRIER();

    for (int c = 0; c < 45; ++c) {
        int cur = c & 1;
        if (c + 1 < 45) STAGE(c + 1, cur ^ 1);   // 2 async DMAs per wave, no VALU tail
#pragma unroll
        for (int k = 0; k < 8; ++k) {
            int p = c * 8 + k;
            float4 t4 = tp[p];                 // uniform -> s_load_dwordx4
            float du = t4.x * (16.0f * DXF);
            float u1 = fmaf(pxj, t4.y, fmaf(pxi, t4.x, t4.z));    // local in W1
            float u2 = fmaf(pxj, t4.y, fmaf(pxi, -t4.x, t4.w));   // local in W2
            const uint2* W1 = &buf[cur][k][0][0];
            const uint2* W2 = &buf[cur][k][1][0];
#pragma unroll
            for (int r = 0; r < 2; ++r) {
                // ---- u1: .x = row p -> T, .y = row 719-p -> M
                int iu1 = (int)u1;                    // u1 in [1,51): trunc == floor
                float f1 = __builtin_amdgcn_fractf(u1);
                half2v pk1 = __builtin_amdgcn_cvt_pkrtz(1.0f - f1, f1);
                uint2 q1 = W1[iu1];                   // one ds_read_b64
                DOT2(accT[r], q1.x, pk1);
                DOT2(accM[r], q1.y, pk1);

                // ---- u2: .x = row p -> M, .y = row 719-p -> T
                int iu2 = (int)u2;
                float f2 = __builtin_amdgcn_fractf(u2);
                half2v pk2 = __builtin_amdgcn_cvt_pkrtz(1.0f - f2, f2);
                uint2 q2 = W2[iu2];                   // one ds_read_b64
                DOT2(accM[r], q2.x, pk2);
                DOT2(accT[r], q2.y, pk2);

                u1 += du;
                u2 -= du;
            }
        }
        WAIT_VM0_BARRIER();                    // drain this chunk's DMAs, swap buffers
    }

    float* orow = out + (size_t)b * (NH * NW);
#pragma unroll
    for (int r = 0; r < 2; ++r) {
        int i = i0 + 16 * r;
        orow[i * NW + j] = accT[r];
        orow[(511 - i) * NW + j] = accM[r];
    }
#undef STAGE
}

extern "C" void kernel_launch(void* const* d_in, const int* in_sizes, int n_in,
                              void* d_out, int out_size, void* d_ws, size_t ws_size,
                              hipStream_t stream) {
    const float* x = (const float*)d_in[0];      // [8,1,720,1024] f32
    const float* w = (const float*)d_in[1];      // [1,1,1,11] f32
    float* out = (float*)d_out;                  // [8,1,512,512] f32

    uint2* G2 = (uint2*)d_ws;                    // 8*360*1024*8 B = 23.6 MB
    float4* tpr = (float4*)((float*)d_ws + (size_t)NB * NPAIR * ND * 2);  // 737 KB

    conv_kernel<<<dim3(NB * NPAIR), dim3(256), 0, stream>>>(x, w, G2);
    table_kernel<<<dim3(180), dim3(256), 0, stream>>>(tpr);
    bp_kernel<<<dim3(1024), dim3(512), 0, stream>>>(G2, tpr, out);
}